// Round 7
// baseline (810.320 us; speedup 1.0000x reference)
//
#include <hip/hip_runtime.h>

typedef __attribute__((ext_vector_type(8))) short bf16x8;
typedef __attribute__((ext_vector_type(4))) float f32x4;
typedef __attribute__((ext_vector_type(8))) unsigned short u16x8;

#define BAR() __builtin_amdgcn_s_barrier()
#define VMC(n) asm volatile("s_waitcnt vmcnt(" #n ")" ::: "memory")
#define SB0() __builtin_amdgcn_sched_barrier(0)
#define WAITL0() do { asm volatile("s_waitcnt lgkmcnt(0)"); SB0(); } while (0)
#define DSRI(dst, base, imm) \
  asm volatile("ds_read_b128 %0, %1 offset:%2" : "=&v"(dst) : "v"(base), "i"(imm))

__device__ inline unsigned short f2bf(float f) {
  unsigned int u = __float_as_uint(f);
  u += 0x7fffu + ((u >> 16) & 1u);
  return (unsigned short)(u >> 16);
}

__device__ inline void gload_lds16(const void* g, void* l) {
  __builtin_amdgcn_global_load_lds(
      (const __attribute__((address_space(1))) void*)g,
      (__attribute__((address_space(3))) void*)l, 16, 0, 0);
}

// ---------------- weight transpose + bf16 cast: W[K][N] -> Wt[N][K] ----------
__global__ void wtrans(const float* __restrict__ W, unsigned short* __restrict__ Wt,
                       int K, int N) {
  int idx = blockIdx.x * 256 + threadIdx.x;
  if (idx >= K * N) return;
  int k = idx / N, n = idx - k * N;
  Wt[(size_t)n * K + k] = f2bf(W[idx]);
}

// ---------------- LayerNorm (+ optional shift/window gather), f32 -> bf16 ----
template <int MODE>
__global__ void ln_k(const float* __restrict__ x, const float* __restrict__ sc,
                     const float* __restrict__ bi, unsigned short* __restrict__ o) {
  int t = blockIdx.x * 4 + (threadIdx.x >> 6);
  int l = threadIdx.x & 63;
  size_t src;
  if (MODE == 0) {
    int b = t / 28800, r = t - b * 28800;
    int win = r / 144, tok = r - win * 144;
    int c1 = win / 100, rem = win - c1 * 100;
    int h1 = rem / 10, w1 = rem - h1 * 10;
    int tc = tok / 72, tr = tok - tc * 72;
    int th = tr / 12, tw = tr - th * 12;
    int cs = c1 * 2 + tc, hs = h1 * 6 + th, wsp = w1 * 12 + tw;
    int co = (cs + 1) & 3;
    int ho = hs + 3; if (ho >= 60) ho -= 60;
    int wo = wsp + 6; if (wo >= 120) wo -= 120;
    src = ((size_t)b * 28800 + (co * 60 + ho) * 120 + wo) * 512;
  } else {
    src = (size_t)t * 512;
  }
  const float4* xr = (const float4*)(x + src);
  float4 v0 = xr[l * 2], v1 = xr[l * 2 + 1];
  float s = v0.x + v0.y + v0.z + v0.w + v1.x + v1.y + v1.z + v1.w;
  float s2 = v0.x * v0.x + v0.y * v0.y + v0.z * v0.z + v0.w * v0.w +
             v1.x * v1.x + v1.y * v1.y + v1.z * v1.z + v1.w * v1.w;
  #pragma unroll
  for (int o2 = 32; o2; o2 >>= 1) {
    s += __shfl_xor(s, o2);
    s2 += __shfl_xor(s2, o2);
  }
  float mean = s * (1.0f / 512.0f);
  float var = s2 * (1.0f / 512.0f) - mean * mean;
  float inv = rsqrtf(var + 1e-6f);
  const float4* scp = (const float4*)sc;
  const float4* bip = (const float4*)bi;
  float4 sa = scp[l * 2], sb = scp[l * 2 + 1];
  float4 ba = bip[l * 2], bb = bip[l * 2 + 1];
  u16x8 ov;
  ov[0] = f2bf((v0.x - mean) * inv * sa.x + ba.x);
  ov[1] = f2bf((v0.y - mean) * inv * sa.y + ba.y);
  ov[2] = f2bf((v0.z - mean) * inv * sa.z + ba.z);
  ov[3] = f2bf((v0.w - mean) * inv * sa.w + ba.w);
  ov[4] = f2bf((v1.x - mean) * inv * sb.x + bb.x);
  ov[5] = f2bf((v1.y - mean) * inv * sb.y + bb.y);
  ov[6] = f2bf((v1.z - mean) * inv * sb.z + bb.z);
  ov[7] = f2bf((v1.w - mean) * inv * sb.w + bb.w);
  *(u16x8*)&o[(size_t)t * 512 + l * 8] = ov;
}

// ---------- 256x256 bf16 MFMA GEMM, fine-phase counted-vmcnt pipeline -------
// A: M x K row-major bf16.  Bt: N x K row-major bf16.
// 512 threads / 8 waves (2M x 4N); wave tile 128x64; BK=32.
// LDS: 4 ring slots x (A 256x32 + B 256x32) = 128 KiB.
// Per K-tile t (buf t&3), 2 phases:
//   phA: 8 ds_read (af0-3, bf0-3) | stage A(t+2) | bar | lgkm0 | 16 MFMA | bar
//   phB: 4 ds_read (af4-7)        | stage B(t+2) | vmcnt(4) | bar | lgkm0 |
//        16 MFMA | bar
// vmcnt(4) once per tile keeps tile t+2's 4 loads in flight (never 0 until
// the t==KT-2 tail).  Stage dest linear; source col pre-swizzled; read addr
// XOR-swizzled (both-sides involution, rule 21).
template <int EPI>
__launch_bounds__(512, 2)
__global__ void gemm8p(const unsigned short* __restrict__ A,
                       const unsigned short* __restrict__ Bt,
                       const float* __restrict__ bias, void* __restrict__ outp,
                       const float* __restrict__ res, int M, int N, int K) {
  __shared__ __attribute__((aligned(16))) unsigned short lds8[4][16384];
  const int tid = threadIdx.x;
  const int w = tid >> 6, l = tid & 63;
  const int wm = w >> 2, wn = w & 3;
  const int lane15 = l & 15;
  const int ntile = N >> 8;
  // bijective XCD-aware swizzle (m204)
  const int nwg = gridDim.x;
  const int q = nwg >> 3, r = nwg & 7;
  const int xcd = blockIdx.x & 7, idx8 = blockIdx.x >> 3;
  const int wgid = (xcd < r ? xcd * (q + 1) : r * (q + 1) + (xcd - r) * q) + idx8;
  const int bm = wgid / ntile, bn = wgid - bm * ntile;
  const int KT = K >> 5;  // K-tiles of 32
  const int Kb = K * 2;   // row stride bytes

  // ---- staging offsets: row = tid>>2 (and +128), col-slot pre-swizzled ----
  const int srow = tid >> 2;
  const int ssl = (tid & 3) ^ ((srow >> 1) & 3);
  const int offAB = srow * Kb + ssl * 16;
  char* const ldsc = (char*)&lds8[0][0];

  const char* gA = (const char*)(A + (size_t)bm * 256 * K);
  const char* gB = (const char*)(Bt + (size_t)bn * 256 * K);

  // ---- LDS read bases (read-side swizzle; row-swz bits == (lane15>>1)&3) ---
  unsigned lds0 = (unsigned)(unsigned long long)
      (__attribute__((address_space(3))) void*)(void*)&lds8[0][0];
  const unsigned swz = (unsigned)((((l >> 4) ^ ((lane15 >> 1) & 3)) << 4));
  const unsigned rA0 = lds0 + (unsigned)((wm * 128 + lane15) * 64) + swz;
  const unsigned rB0 = lds0 + 16384u + (unsigned)((wn * 64 + lane15) * 64) + swz;

  f32x4 acc[8][4] = {};
  bf16x8 af[4], bf[4];

  auto STAGE_A = [&](int bufi, const char* gat) {
    char* dst = ldsc + bufi * 32768 + w * 1024;
    gload_lds16(gat + offAB, dst);
    gload_lds16(gat + offAB + 128 * Kb, dst + 8192);
  };
  auto STAGE_B = [&](int bufi, const char* gbt) {
    char* dst = ldsc + bufi * 32768 + 16384 + w * 1024;
    gload_lds16(gbt + offAB, dst);
    gload_lds16(gbt + offAB + 128 * Kb, dst + 8192);
  };

  // prologue: stage tiles 0 and 1 (order A0,B0,A1,B1)
  STAGE_A(0, gA); STAGE_B(0, gB);
  STAGE_A(1, gA + 64); STAGE_B(1, gB + 64);
  VMC(4);  // tile 0 resident; tile 1 in flight
  BAR();

  for (int t = 0; t < KT; ++t) {
    const unsigned boff = (unsigned)((t & 3) << 15);
    const unsigned rAb = rA0 + boff, rBb = rB0 + boff;
    const bool st = (t + 2 < KT);
    const int bufS = (t + 2) & 3;
    const char* gAt = gA + (size_t)(t + 2) * 64;
    const char* gBt = gB + (size_t)(t + 2) * 64;
    // ---- phase A: af0-3 + bf0-3, stage A(t+2) ----
    DSRI(af[0], rAb, 0);    DSRI(af[1], rAb, 1024);
    DSRI(af[2], rAb, 2048); DSRI(af[3], rAb, 3072);
    DSRI(bf[0], rBb, 0);    DSRI(bf[1], rBb, 1024);
    DSRI(bf[2], rBb, 2048); DSRI(bf[3], rBb, 3072);
    if (st) STAGE_A(bufS, gAt);
    BAR();
    WAITL0();
    __builtin_amdgcn_s_setprio(1);
    #pragma unroll
    for (int mi = 0; mi < 4; ++mi)
      #pragma unroll
      for (int nf = 0; nf < 4; ++nf)
        acc[mi][nf] = __builtin_amdgcn_mfma_f32_16x16x32_bf16(
            af[mi], bf[nf], acc[mi][nf], 0, 0, 0);
    __builtin_amdgcn_s_setprio(0);
    BAR();
    // ---- phase B: af4-7 (reuse regs), stage B(t+2), counted vmcnt ----
    DSRI(af[0], rAb, 4096); DSRI(af[1], rAb, 5120);
    DSRI(af[2], rAb, 6144); DSRI(af[3], rAb, 7168);
    if (st) STAGE_B(bufS, gBt);
    if (t < KT - 2) { VMC(4); } else if (t == KT - 2) { VMC(0); }
    BAR();
    WAITL0();
    __builtin_amdgcn_s_setprio(1);
    #pragma unroll
    for (int mi = 0; mi < 4; ++mi)
      #pragma unroll
      for (int nf = 0; nf < 4; ++nf)
        acc[4 + mi][nf] = __builtin_amdgcn_mfma_f32_16x16x32_bf16(
            af[mi], bf[nf], acc[4 + mi][nf], 0, 0, 0);
    __builtin_amdgcn_s_setprio(0);
    BAR();
  }

  // ---------------- epilogue ----------------
  float* outf = (float*)outp;
  unsigned short* outh = (unsigned short*)outp;
  #pragma unroll
  for (int mi = 0; mi < 8; ++mi) {
    #pragma unroll
    for (int j = 0; j < 4; ++j) {
      int grow = bm * 256 + wm * 128 + mi * 16 + ((l >> 4) << 2) + j;
      int win = 0, tok = 0;
      size_t rowbase = 0;
      if constexpr (EPI == 0) {
        win = grow / 144;
        tok = grow - win * 144;
      } else if constexpr (EPI == 1) {
        win = grow / 144;
        tok = grow - win * 144;
        int b = win / 200, wl = win - b * 200;
        int c1 = wl / 100, rem = wl - c1 * 100;
        int h1 = rem / 10, w1 = rem - h1 * 10;
        int tc = tok / 72, tr = tok - tc * 72;
        int th = tr / 12, tw = tr - th * 12;
        int cs = c1 * 2 + tc, hs = h1 * 6 + th, wsp = w1 * 12 + tw;
        int co = (cs + 1) & 3;
        int ho = hs + 3; if (ho >= 60) ho -= 60;
        int wo = wsp + 6; if (wo >= 120) wo -= 120;
        rowbase = ((size_t)b * 28800 + (co * 60 + ho) * 120 + wo) * 512;
      }
      #pragma unroll
      for (int nf = 0; nf < 4; ++nf) {
        int gcol = bn * 256 + wn * 64 + nf * 16 + lane15;
        float val = acc[mi][nf][j] + bias[gcol];
        if constexpr (EPI == 0) {
          int which = gcol >> 9, hd = (gcol >> 6) & 7, dh = gcol & 63;
          outh[(((size_t)(win * 3 + which) * 8 + hd) * 144 + tok) * 64 + dh] = f2bf(val);
        } else if constexpr (EPI == 1) {
          size_t oi = rowbase + gcol;
          outf[oi] = res[oi] + val;
        } else if constexpr (EPI == 2) {
          float u = 0.7978845608f * (val + 0.044715f * val * val * val);
          float g = val / (1.0f + __expf(-2.0f * u));
          outh[(size_t)grow * N + gcol] = f2bf(g);
        } else {
          size_t oi = (size_t)grow * N + gcol;
          outf[oi] += val;
        }
      }
    }
  }
}

// ---------------- attention: one block per (window, head) -------------------
__launch_bounds__(576)
__global__ void attn_k(const unsigned short* __restrict__ qkv,
                       unsigned short* __restrict__ owin) {
  __shared__ __attribute__((aligned(16))) unsigned short Ks[144 * 72];
  __shared__ __attribute__((aligned(16))) unsigned short Vt[64 * 168];
  __shared__ __attribute__((aligned(16))) unsigned short Ps[144 * 168];
  __shared__ unsigned char gid[144];
  int bid = blockIdx.x;
  int win = bid >> 3, head = bid & 7;
  const unsigned short* qb = qkv + ((size_t)(win * 3 + 0) * 8 + head) * (144 * 64);
  const unsigned short* kb = qkv + ((size_t)(win * 3 + 1) * 8 + head) * (144 * 64);
  const unsigned short* vb = qkv + ((size_t)(win * 3 + 2) * 8 + head) * (144 * 64);
  int tid = threadIdx.x;
  {
    int row = tid >> 2, c0 = (tid & 3) << 4;
    u16x8 ka = *(const u16x8*)(kb + row * 64 + c0);
    u16x8 kc = *(const u16x8*)(kb + row * 64 + c0 + 8);
    *(u16x8*)&Ks[row * 72 + c0] = ka;
    *(u16x8*)&Ks[row * 72 + c0 + 8] = kc;
    u16x8 va = *(const u16x8*)(vb + row * 64 + c0);
    u16x8 vc = *(const u16x8*)(vb + row * 64 + c0 + 8);
    #pragma unroll
    for (int j = 0; j < 8; ++j) Vt[(c0 + j) * 168 + row] = va[j];
    #pragma unroll
    for (int j = 0; j < 8; ++j) Vt[(c0 + 8 + j) * 168 + row] = vc[j];
  }
  for (int i = tid; i < 64 * 24; i += 576) {
    int d = i / 24, m = i - d * 24;
    Vt[d * 168 + 144 + m] = 0;
  }
  for (int i = tid; i < 144 * 24; i += 576) {
    int r = i / 24, c = i - r * 24;
    Ps[r * 168 + 144 + c] = 0;
  }
  if (tid < 144) {
    int wl = win % 200;
    int c1 = wl / 100, rem = wl - c1 * 100;
    int h1 = rem / 10, w1 = rem - h1 * 10;
    int tc = tid / 72, tr = tid - tc * 72;
    int th = tr / 12, tw = tr - th * 12;
    int cs = c1 * 2 + tc, hs = h1 * 6 + th, wsp = w1 * 12 + tw;
    int rc = cs < 2 ? 0 : (cs < 3 ? 1 : 2);
    int rh = hs < 54 ? 0 : (hs < 57 ? 1 : 2);
    int rw = wsp < 108 ? 0 : (wsp < 114 ? 1 : 2);
    if (rw == 1) rw = 2;
    gid[tid] = (unsigned char)(rc * 9 + rh * 3 + rw);
  }
  __syncthreads();
  int wv = tid >> 6, l = tid & 63;
  int lane15 = l & 15, lk = (l >> 4) << 3;
  bf16x8 aq0 = *(const bf16x8*)(qb + (wv * 16 + lane15) * 64 + lk);
  bf16x8 aq1 = *(const bf16x8*)(qb + (wv * 16 + lane15) * 64 + 32 + lk);
  f32x4 sf[9];
  #pragma unroll
  for (int ct = 0; ct < 9; ++ct) {
    f32x4 z = {};
    bf16x8 b0 = *(const bf16x8*)&Ks[(ct * 16 + lane15) * 72 + lk];
    bf16x8 b1 = *(const bf16x8*)&Ks[(ct * 16 + lane15) * 72 + 32 + lk];
    z = __builtin_amdgcn_mfma_f32_16x16x32_bf16(aq0, b0, z, 0, 0, 0);
    z = __builtin_amdgcn_mfma_f32_16x16x32_bf16(aq1, b1, z, 0, 0, 0);
    sf[ct] = z;
  }
  int gi[4];
  #pragma unroll
  for (int j = 0; j < 4; ++j) gi[j] = gid[wv * 16 + ((l >> 4) << 2) + j];
  float mx[4] = {-1e30f, -1e30f, -1e30f, -1e30f};
  #pragma unroll
  for (int ct = 0; ct < 9; ++ct) {
    int gj = gid[ct * 16 + lane15];
    #pragma unroll
    for (int j = 0; j < 4; ++j) {
      float s = sf[ct][j] * 0.125f;
      if (gj != gi[j]) s = -1e30f;
      sf[ct][j] = s;
      mx[j] = fmaxf(mx[j], s);
    }
  }
  #pragma unroll
  for (int o2 = 8; o2; o2 >>= 1)
    #pragma unroll
    for (int j = 0; j < 4; ++j) mx[j] = fmaxf(mx[j], __shfl_xor(mx[j], o2));
  float sm[4] = {0.f, 0.f, 0.f, 0.f};
  #pragma unroll
  for (int ct = 0; ct < 9; ++ct)
    #pragma unroll
    for (int j = 0; j < 4; ++j) {
      float e = __expf(sf[ct][j] - mx[j]);
      sf[ct][j] = e;
      sm[j] += e;
    }
  #pragma unroll
  for (int o2 = 8; o2; o2 >>= 1)
    #pragma unroll
    for (int j = 0; j < 4; ++j) sm[j] += __shfl_xor(sm[j], o2);
  float rs[4];
  #pragma unroll
  for (int j = 0; j < 4; ++j) rs[j] = 1.0f / sm[j];
  #pragma unroll
  for (int ct = 0; ct < 9; ++ct)
    #pragma unroll
    for (int j = 0; j < 4; ++j)
      Ps[(wv * 16 + ((l >> 4) << 2) + j) * 168 + ct * 16 + lane15] =
          f2bf(sf[ct][j] * rs[j]);
  __syncthreads();
  f32x4 of[4] = {};
  #pragma unroll
  for (int ks = 0; ks < 5; ++ks) {
    bf16x8 ap = *(const bf16x8*)&Ps[(wv * 16 + lane15) * 168 + ks * 32 + lk];
    #pragma unroll
    for (int nt = 0; nt < 4; ++nt) {
      bf16x8 bv = *(const bf16x8*)&Vt[(nt * 16 + lane15) * 168 + ks * 32 + lk];
      of[nt] = __builtin_amdgcn_mfma_f32_16x16x32_bf16(ap, bv, of[nt], 0, 0, 0);
    }
  }
  unsigned short* ob = owin + (size_t)win * 144 * 512 + head * 64;
  #pragma unroll
  for (int nt = 0; nt < 4; ++nt)
    #pragma unroll
    for (int j = 0; j < 4; ++j) {
      int row = wv * 16 + ((l >> 4) << 2) + j;
      ob[(size_t)row * 512 + nt * 16 + lane15] = f2bf(of[nt][j]);
    }
}

extern "C" void kernel_launch(void* const* d_in, const int* in_sizes, int n_in,
                              void* d_out, int out_size, void* d_ws, size_t ws_size,
                              hipStream_t stream) {
  const float* x = (const float*)d_in[0];
  const float* qkv_w = (const float*)d_in[1];
  const float* qkv_b = (const float*)d_in[2];
  const float* proj_w = (const float*)d_in[3];
  const float* proj_b = (const float*)d_in[4];
  const float* n1s = (const float*)d_in[5];
  const float* n1b = (const float*)d_in[6];
  const float* n2s = (const float*)d_in[7];
  const float* n2b = (const float*)d_in[8];
  const float* w1 = (const float*)d_in[9];
  const float* b1 = (const float*)d_in[10];
  const float* w2 = (const float*)d_in[11];
  const float* b2 = (const float*)d_in[12];
  float* out = (float*)d_out;
  char* ws = (char*)d_ws;

  unsigned short* WqT = (unsigned short*)(ws);               // 1536x512
  unsigned short* WpT = (unsigned short*)(ws + 1572864);     // 512x512
  unsigned short* W1T = (unsigned short*)(ws + 2097152);     // 2048x512
  unsigned short* W2T = (unsigned short*)(ws + 4194304);     // 512x2048
  unsigned short* hwin = (unsigned short*)(ws + 6291456);    // 57600x512 (also ln2out)
  unsigned short* qkvb = (unsigned short*)(ws + 65273856);   // 57600x1536
  unsigned short* owin = (unsigned short*)(ws + 242221056);  // 57600x512
  unsigned short* mid = qkvb;                                // 57600x2048 (aliases qkv+owin)

  wtrans<<<(512 * 1536 + 255) / 256, 256, 0, stream>>>(qkv_w, WqT, 512, 1536);
  wtrans<<<(512 * 512 + 255) / 256, 256, 0, stream>>>(proj_w, WpT, 512, 512);
  wtrans<<<(512 * 2048 + 255) / 256, 256, 0, stream>>>(w1, W1T, 512, 2048);
  wtrans<<<(2048 * 512 + 255) / 256, 256, 0, stream>>>(w2, W2T, 2048, 512);
  ln_k<0><<<14400, 256, 0, stream>>>(x, n1s, n1b, hwin);
  gemm8p<0><<<225 * 6, 512, 0, stream>>>(hwin, WqT, qkv_b, qkvb, nullptr, 57600, 1536, 512);
  attn_k<<<3200, 576, 0, stream>>>(qkvb, owin);
  gemm8p<1><<<225 * 2, 512, 0, stream>>>(owin, WpT, proj_b, out, x, 57600, 512, 512);
  ln_k<1><<<14400, 256, 0, stream>>>(out, n2s, n2b, hwin);
  gemm8p<2><<<225 * 8, 512, 0, stream>>>(hwin, W1T, b1, mid, nullptr, 57600, 2048, 512);
  gemm8p<3><<<225 * 2, 512, 0, stream>>>(mid, W2T, b2, out, nullptr, 57600, 512, 2048);
}